// Round 2
// baseline (724.317 us; speedup 1.0000x reference)
//
#include <hip/hip_runtime.h>
#include <hip/hip_bf16.h>

typedef __attribute__((ext_vector_type(8))) short short8;   // 8 bf16
typedef __attribute__((ext_vector_type(4))) float f32x4;
typedef __attribute__((ext_vector_type(16))) float f32x16;
typedef __attribute__((ext_vector_type(4))) unsigned int u32x4;
typedef unsigned int u32;
typedef unsigned short u16;

#define C_ 256
#define G_ 32
#define ND_ 18432          // D*H*W per batch
#define HW_ 2304           // 48*48
#define EPS_ 1e-5f
// (C/8)^-0.5 * log2(e): softmax scale pre-folded with exp2 conversion
#define QS2_ 0.25503487f

static __device__ __forceinline__ u16 f2bf(float f) {
  __hip_bfloat16 h = __float2bfloat16(f);
  return __builtin_bit_cast(u16, h);
}

// ---------------- weights f32 -> bf16 ----------------
__global__ void k_convert_w(const float* __restrict__ qkv_w,
                            const float* __restrict__ proj_w,
                            u16* __restrict__ wout) {
  int i = blockIdx.x * 256 + threadIdx.x;   // grid 1024 -> 262144 exactly
  if (i < 196608) wout[i] = f2bf(qkv_w[i]);
  else            wout[i] = f2bf(proj_w[i - 196608]);
}

// ---------------- GroupNorm stats: one block per (b,g) ----------------
__global__ __launch_bounds__(1024) void k_gn_stats(const float* __restrict__ x,
                                                   float* __restrict__ stats) {
  int grp = blockIdx.x;  // b*32+g ; 8 channels * 18432 contiguous f32
  const float4* p = (const float4*)(x + (size_t)grp * 147456);
  float s1 = 0.f, s2 = 0.f;
  for (int i = threadIdx.x; i < 36864; i += 1024) {
    float4 v = p[i];
    s1 += v.x + v.y + v.z + v.w;
    s2 += v.x*v.x + v.y*v.y + v.z*v.z + v.w*v.w;
  }
  for (int off = 1; off < 64; off <<= 1) {
    s1 += __shfl_xor(s1, off, 64);
    s2 += __shfl_xor(s2, off, 64);
  }
  __shared__ float ls1[16], ls2[16];
  int wid = threadIdx.x >> 6;
  if ((threadIdx.x & 63) == 0) { ls1[wid] = s1; ls2[wid] = s2; }
  __syncthreads();
  if (threadIdx.x == 0) {
    float a = 0.f, b = 0.f;
    for (int i = 0; i < 16; i++) { a += ls1[i]; b += ls2[i]; }
    float mu  = a / 147456.0f;
    float var = b / 147456.0f - mu * mu;
    stats[grp * 2]     = mu;
    stats[grp * 2 + 1] = rsqrtf(var + EPS_);
  }
}

// ---------------- normalize + transpose: x[b][c][n] f32 -> h_t[b][n][c] bf16 ----------------
__global__ __launch_bounds__(256) void k_tnorm(const float* __restrict__ x,
                                               const float* __restrict__ stats,
                                               const float* __restrict__ nw,
                                               const float* __restrict__ nb,
                                               u16* __restrict__ h_t) {
  __shared__ u16 tl[64 * 66];
  int wg = blockIdx.x;          // 2304 = b(2) * ct(4) * nt(288)
  int nt = wg % 288; int ct = (wg / 288) & 3; int b = wg / 1152;
  int c0 = ct * 64, n0 = nt * 64;
  int tid = threadIdx.x;
#pragma unroll
  for (int p = 0; p < 4; p++) {
    int c_l = p * 16 + (tid >> 4);
    int n4  = (tid & 15) * 4;
    int cg  = c0 + c_l;
    float4 v = *(const float4*)(x + ((size_t)(b * C_ + cg)) * ND_ + n0 + n4);
    float mu = stats[(b * G_ + (cg >> 3)) * 2];
    float rs = stats[(b * G_ + (cg >> 3)) * 2 + 1];
    float w = nw[cg], bia = nb[cg];
    tl[(n4 + 0) * 66 + c_l] = f2bf((v.x - mu) * rs * w + bia);
    tl[(n4 + 1) * 66 + c_l] = f2bf((v.y - mu) * rs * w + bia);
    tl[(n4 + 2) * 66 + c_l] = f2bf((v.z - mu) * rs * w + bia);
    tl[(n4 + 3) * 66 + c_l] = f2bf((v.w - mu) * rs * w + bia);
  }
  __syncthreads();
#pragma unroll
  for (int p = 0; p < 2; p++) {
    int idx = p * 256 + tid;
    int n_l = idx >> 3, c8 = idx & 7;
    const u32* s = (const u32*)((const char*)tl + n_l * 132 + c8 * 16);
    uint4 vv; vv.x = s[0]; vv.y = s[1]; vv.z = s[2]; vv.w = s[3];
    *(uint4*)(h_t + ((size_t)(b * ND_ + n0 + n_l)) * C_ + c0 + c8 * 8) = vv;
  }
}

// ---------------- QK GEMM (swapped: A=H [n x c], B=W^T [c x o]) ----------------
__global__ __launch_bounds__(256) void k_qk(const u16* __restrict__ h_t,
                                            const u16* __restrict__ w_qkv,
                                            const float* __restrict__ qkv_b,
                                            u16* __restrict__ q_ws,
                                            u16* __restrict__ k_ws) {
  int wg = blockIdx.x;
  int nt = wg % 288; int ot = (wg / 288) & 3; int b = wg / 1152;
  int n0 = nt * 64, o0 = ot * 128;
  int lane = threadIdx.x & 63; int w = threadIdx.x >> 6;
  int g = lane >> 4, lid = lane & 15;
  int n_w = n0 + w * 16;
  f32x4 acc[8];
#pragma unroll
  for (int t = 0; t < 8; t++) acc[t] = (f32x4){0.f, 0.f, 0.f, 0.f};
  const short8* Ab = (const short8*)(h_t + ((size_t)(b * ND_ + n_w + lid)) * C_ + g * 8);
#pragma unroll
  for (int ks = 0; ks < 8; ks++) {
    short8 a = Ab[ks * 4];
#pragma unroll
    for (int t = 0; t < 8; t++) {
      short8 bf = *(const short8*)(w_qkv + ((size_t)(o0 + t * 16 + lid)) * C_ + ks * 32 + g * 8);
      acc[t] = __builtin_amdgcn_mfma_f32_16x16x32_bf16(a, bf, acc[t], 0, 0, 0);
    }
  }
#pragma unroll
  for (int t = 0; t < 8; t++) {
    int o_t = o0 + t * 16;
    float bias = qkv_b[o_t + lid];
    bool isq = (o_t < 256);
    float mul = isq ? QS2_ : 1.0f;
    u16* dst = isq ? q_ws : k_ws;
    int oc = isq ? (o_t + lid) : (o_t - 256 + lid);
#pragma unroll
    for (int r = 0; r < 4; r++) {
      int n_idx = n_w + g * 4 + r;
      dst[((size_t)(b * ND_ + n_idx)) * C_ + oc] = f2bf((acc[t][r] + bias) * mul);
    }
  }
}

// ---------------- V GEMM -> v2 group-major [slice][grp][slot(6)][c(256)][8] ----------------
__global__ __launch_bounds__(256) void k_v(const u16* __restrict__ h_t,
                                           const u16* __restrict__ w_qkv,
                                           const float* __restrict__ qkv_b,
                                           u16* __restrict__ v_ws) {
  int wg = blockIdx.x;
  int nt = wg % 144; int ot = (wg / 144) & 3; int b = wg / 576;
  int n0 = nt * 128, o0 = ot * 64;
  int lane = threadIdx.x & 63; int w = threadIdx.x >> 6;
  int g = lane >> 4, lid = lane & 15;
  int o_w = o0 + w * 16;
  f32x4 acc[8];
#pragma unroll
  for (int t = 0; t < 8; t++) acc[t] = (f32x4){0.f, 0.f, 0.f, 0.f};
  const short8* Ab = (const short8*)(w_qkv + ((size_t)(512 + o_w + lid)) * C_ + g * 8);
#pragma unroll
  for (int ks = 0; ks < 8; ks++) {
    short8 a = Ab[ks * 4];
#pragma unroll
    for (int t = 0; t < 8; t++) {
      short8 bf = *(const short8*)(h_t + ((size_t)(b * ND_ + n0 + t * 16 + lid)) * C_ + ks * 32 + g * 8);
      acc[t] = __builtin_amdgcn_mfma_f32_16x16x32_bf16(a, bf, acc[t], 0, 0, 0);
    }
  }
#pragma unroll
  for (int t = 0; t < 8; t++) {
#pragma unroll
    for (int r = 0; r < 4; r++) {
      int o = o_w + g * 4 + r;
      int n = n0 + t * 16 + lid;
      int d = n / 2304; int hw = n % 2304;
      int grp = hw / 48; int j = hw % 48;
      size_t idx = ((size_t)(((b * 8 + d) * 48 + grp) * 6 + (j >> 3))) * 2048 + o * 8 + (j & 7);
      v_ws[idx] = f2bf(acc[t][r] + qkv_b[512 + o]);
    }
  }
}

// ---------------- fused attention: 288 blocks, 4 waves x 32q, KVBLK=96 ----------------
__global__ __launch_bounds__(256) void k_attn(const u16* __restrict__ q_ws,
                                              const u16* __restrict__ k_ws,
                                              const u16* __restrict__ v_ws,
                                              u16* __restrict__ ao) {
  __shared__ __align__(16) unsigned char lds[114688]; // K [96][512B] @0 ; V [256][256B] @49152
  int wg = blockIdx.x;
  int virt = (wg & 7) * 36 + (wg >> 3);   // XCD-chunked swizzle (288 = 8*36)
  int qt = virt % 18; int slice = virt / 18;
  int b = slice >> 3, d = slice & 7;
  int tid = threadIdx.x;
  int lane = tid & 63, w = tid >> 6;
  int l31 = lane & 31, hi = lane >> 5;
  unsigned char* klds = lds;
  unsigned char* vlds = lds + 49152;

  const char* kgb = (const char*)k_ws + (size_t)(b * ND_ + d * HW_) * 512;
  const char* vgb = (const char*)v_ws + (size_t)(b * 8 + d) * 1179648;

  int krow0 = tid >> 5;          // [0,8)
  int kslot = tid & 31;
  int swz = (l31 & 15) << 4;

  // Q fragments (32 q per wave, hoisted; includes softmax*log2e prescale)
  int qpos = b * ND_ + d * HW_ + qt * 128 + w * 32 + l31;
  const char* qp = (const char*)q_ws + (size_t)qpos * 512 + hi * 16;
  short8 qf[16];
#pragma unroll
  for (int ks = 0; ks < 16; ks++) qf[ks] = *(const short8*)(qp + ks * 32);

  // prologue: stage tile 0
  {
    uint4 kr[12], vr[12];
#pragma unroll
    for (int i = 0; i < 12; i++)
      kr[i] = *(const uint4*)(kgb + (size_t)(krow0 + 8 * i) * 512 + kslot * 16);
#pragma unroll
    for (int i = 0; i < 12; i++)
      vr[i] = *(const uint4*)(vgb + (i >= 6 ? 24576 : 0) + (i % 6) * 4096 + tid * 16);
#pragma unroll
    for (int i = 0; i < 12; i++)
      *(uint4*)(klds + (size_t)(krow0 + 8 * i) * 512 + ((kslot ^ (krow0 + 8 * (i & 1))) << 4)) = kr[i];
#pragma unroll
    for (int i = 0; i < 12; i++)
      *(uint4*)(vlds + (size_t)tid * 256 + ((i ^ (tid & 15)) << 4)) = vr[i];
  }
  __syncthreads();

  f32x16 acc[8];
#pragma unroll
  for (int i = 0; i < 8; i++) acc[i] = (f32x16)0.0f;

  for (int t = 0; t < 24; t++) {
    // T14: issue next-tile global loads early; ds_write after barrier
    uint4 kr[12], vr[12];
    if (t < 23) {
      const char* kg = kgb + (size_t)(t + 1) * 49152;
      const char* vg = vgb + (size_t)(t + 1) * 49152;
#pragma unroll
      for (int i = 0; i < 12; i++)
        kr[i] = *(const uint4*)(kg + (size_t)(krow0 + 8 * i) * 512 + kslot * 16);
#pragma unroll
      for (int i = 0; i < 12; i++)
        vr[i] = *(const uint4*)(vg + (i >= 6 ? 24576 : 0) + (i % 6) * 4096 + tid * 16);
    }

    // QK^T swapped: S[k 96][q 32] = K * Q, contraction over 256 ch
    f32x16 S0 = (f32x16)0.0f, S1 = (f32x16)0.0f, S2 = (f32x16)0.0f;
#pragma unroll
    for (int ks = 0; ks < 16; ks++) {
      int off = (ks * 32 + hi * 16) ^ swz;
      short8 k0 = *(const short8*)(klds + (size_t)(l31) * 512 + off);
      short8 k1 = *(const short8*)(klds + (size_t)(l31 + 32) * 512 + off);
      short8 k2 = *(const short8*)(klds + (size_t)(l31 + 64) * 512 + off);
      S0 = __builtin_amdgcn_mfma_f32_32x32x16_bf16(k0, qf[ks], S0, 0, 0, 0);
      S1 = __builtin_amdgcn_mfma_f32_32x32x16_bf16(k1, qf[ks], S1, 0, 0, 0);
      S2 = __builtin_amdgcn_mfma_f32_32x32x16_bf16(k2, qf[ks], S2, 0, 0, 0);
    }

    // exact softmax, 2 groups of 48 keys; lane-local except one shfl per group.
    // no max subtraction needed: |S*log2e| <~ 25, exp2 safe in f32.
#pragma unroll
    for (int r = 0; r < 16; r++) {
      S0[r] = __builtin_amdgcn_exp2f(S0[r]);
      S1[r] = __builtin_amdgcn_exp2f(S1[r]);
      S2[r] = __builtin_amdgcn_exp2f(S2[r]);
    }
    float zA = 0.f, zB = 0.f;
#pragma unroll
    for (int r = 0; r < 16; r++) { zA += S0[r]; zB += S2[r]; }
#pragma unroll
    for (int r = 0; r < 8; r++)  { zA += S1[r]; zB += S1[r + 8]; }
    zA += __shfl_xor(zA, 32, 64);
    zB += __shfl_xor(zB, 32, 64);
    float iA = __builtin_amdgcn_rcpf(zA);
    float iB = __builtin_amdgcn_rcpf(zB);
#pragma unroll
    for (int r = 0; r < 16; r++) {
      S0[r] *= iA;
      S2[r] *= iB;
      S1[r] *= (r < 8) ? iA : iB;
    }

    // P -> PV A-fragments in-register (cvt_pk + permlane32_swap, T12)
    short8 pa[6];
#pragma unroll
    for (int s = 0; s < 6; s++) {
      const f32x16& P = (s < 2) ? S0 : (s < 4) ? S1 : S2;
      const int a = (s & 1) * 8;
      u32 u0, u1, v0, v1;
      asm("v_cvt_pk_bf16_f32 %0, %1, %2" : "=v"(u0) : "v"(P[a + 0]), "v"(P[a + 1]));
      asm("v_cvt_pk_bf16_f32 %0, %1, %2" : "=v"(u1) : "v"(P[a + 2]), "v"(P[a + 3]));
      asm("v_cvt_pk_bf16_f32 %0, %1, %2" : "=v"(v0) : "v"(P[a + 4]), "v"(P[a + 5]));
      asm("v_cvt_pk_bf16_f32 %0, %1, %2" : "=v"(v1) : "v"(P[a + 6]), "v"(P[a + 7]));
      asm("v_permlane32_swap_b32 %0, %1" : "+v"(u0), "+v"(v0));
      asm("v_permlane32_swap_b32 %0, %1" : "+v"(u1), "+v"(v1));
      u32x4 wv; wv[0] = u0; wv[1] = u1; wv[2] = v0; wv[3] = v1;
      pa[s] = __builtin_bit_cast(short8, wv);
    }

    // PV: out[q 32][c 256] += P^T * V
#pragma unroll
    for (int s = 0; s < 6; s++) {
      int off = (s * 32 + hi * 16) ^ swz;
#pragma unroll
      for (int ct = 0; ct < 8; ct++) {
        short8 vf = *(const short8*)(vlds + (size_t)(ct * 32 + l31) * 256 + off);
        acc[ct] = __builtin_amdgcn_mfma_f32_32x32x16_bf16(pa[s], vf, acc[ct], 0, 0, 0);
      }
    }

    __syncthreads();
    if (t < 23) {
#pragma unroll
      for (int i = 0; i < 12; i++)
        *(uint4*)(klds + (size_t)(krow0 + 8 * i) * 512 + ((kslot ^ (krow0 + 8 * (i & 1))) << 4)) = kr[i];
#pragma unroll
      for (int i = 0; i < 12; i++)
        *(uint4*)(vlds + (size_t)tid * 256 + ((i ^ (tid & 15)) << 4)) = vr[i];
    }
    __syncthreads();
  }

  // epilogue: D layout col=lane&31 (=c), row=(r&3)+8*(r>>2)+4*hi (=q)
  size_t ob = ((size_t)(b * ND_ + d * HW_ + qt * 128 + w * 32)) * 256;
#pragma unroll
  for (int ct = 0; ct < 8; ct++) {
#pragma unroll
    for (int r = 0; r < 16; r++) {
      int ql = (r & 3) + 8 * (r >> 2) + 4 * hi;
      ao[ob + (size_t)ql * 256 + ct * 32 + l31] = f2bf(acc[ct][r]);
    }
  }
}

// ---------------- proj + bias + residual -> d_out f32 channel-major ----------------
__global__ __launch_bounds__(256) void k_proj(const u16* __restrict__ ao,
                                              const u16* __restrict__ w_p,
                                              const float* __restrict__ proj_b,
                                              const float* __restrict__ x,
                                              float* __restrict__ out) {
  int wg = blockIdx.x;
  int nt = wg % 144; int ot = (wg / 144) & 3; int b = wg / 576;
  int n0 = nt * 128, o0 = ot * 64;
  int lane = threadIdx.x & 63; int w = threadIdx.x >> 6;
  int g = lane >> 4, lid = lane & 15;
  int o_w = o0 + w * 16;
  f32x4 acc[8];
#pragma unroll
  for (int t = 0; t < 8; t++) acc[t] = (f32x4){0.f, 0.f, 0.f, 0.f};
  const short8* Ab = (const short8*)(w_p + ((size_t)(o_w + lid)) * C_ + g * 8);
#pragma unroll
  for (int ks = 0; ks < 8; ks++) {
    short8 a = Ab[ks * 4];
#pragma unroll
    for (int t = 0; t < 8; t++) {
      short8 bf = *(const short8*)(ao + ((size_t)(b * ND_ + n0 + t * 16 + lid)) * C_ + ks * 32 + g * 8);
      acc[t] = __builtin_amdgcn_mfma_f32_16x16x32_bf16(a, bf, acc[t], 0, 0, 0);
    }
  }
#pragma unroll
  for (int t = 0; t < 8; t++) {
#pragma unroll
    for (int r = 0; r < 4; r++) {
      int o = o_w + g * 4 + r;
      size_t off = ((size_t)(b * C_ + o)) * ND_ + n0 + t * 16 + lid;
      out[off] = acc[t][r] + proj_b[o] + x[off];
    }
  }
}

extern "C" void kernel_launch(void* const* d_in, const int* in_sizes, int n_in,
                              void* d_out, int out_size, void* d_ws, size_t ws_size,
                              hipStream_t stream) {
  const float* x      = (const float*)d_in[0];
  const float* norm_w = (const float*)d_in[1];
  const float* norm_b = (const float*)d_in[2];
  const float* qkv_w  = (const float*)d_in[3];
  const float* qkv_b  = (const float*)d_in[4];
  const float* proj_w = (const float*)d_in[5];
  const float* proj_b = (const float*)d_in[6];

  char* ws = (char*)d_ws;
  float* stats = (float*)ws;
  u16* w_qkv = (u16*)(ws + 1024);
  u16* w_p   = (u16*)(ws + 1024 + 393216);
  u16* h_t   = (u16*)(ws + 525312);
  u16* q_ws  = h_t + 9437184;
  u16* k_ws  = q_ws + 9437184;
  u16* v_ws  = k_ws + 9437184;
  u16* ao    = h_t;  // alias: h_t dead after k_v
  float* out = (float*)d_out;

  if (ws_size < (size_t)525312 + 4ull * 9437184ull * 2ull) return;

  hipLaunchKernelGGL(k_convert_w, dim3(1024), dim3(256), 0, stream, qkv_w, proj_w, w_qkv);
  hipLaunchKernelGGL(k_gn_stats,  dim3(64),   dim3(1024), 0, stream, x, stats);
  hipLaunchKernelGGL(k_tnorm,     dim3(2304), dim3(256), 0, stream, x, stats, norm_w, norm_b, h_t);
  hipLaunchKernelGGL(k_qk,        dim3(2304), dim3(256), 0, stream, h_t, w_qkv, qkv_b, q_ws, k_ws);
  hipLaunchKernelGGL(k_v,         dim3(1152), dim3(256), 0, stream, h_t, w_qkv, qkv_b, v_ws);
  hipLaunchKernelGGL(k_attn,      dim3(288),  dim3(256), 0, stream, q_ws, k_ws, v_ws, ao);
  hipLaunchKernelGGL(k_proj,      dim3(1152), dim3(256), 0, stream, ao, w_p, proj_b, x, out);
}

// Round 3
// 433.803 us; speedup vs baseline: 1.6697x; 1.6697x over previous
//
#include <hip/hip_runtime.h>
#include <hip/hip_bf16.h>

typedef __attribute__((ext_vector_type(8))) short short8;   // 8 bf16
typedef __attribute__((ext_vector_type(4))) float f32x4;
typedef __attribute__((ext_vector_type(16))) float f32x16;
typedef __attribute__((ext_vector_type(4))) unsigned int u32x4;
typedef unsigned int u32;
typedef unsigned short u16;

#define C_ 256
#define G_ 32
#define ND_ 18432          // D*H*W per batch
#define HW_ 2304           // 48*48
#define EPS_ 1e-5f
// (C/8)^-0.5 * log2(e): softmax scale pre-folded with exp2 conversion
#define QS2_ 0.25503487f

static __device__ __forceinline__ u16 f2bf(float f) {
  __hip_bfloat16 h = __float2bfloat16(f);
  return __builtin_bit_cast(u16, h);
}

static __device__ __forceinline__ void gll16(const void* g, void* l) {
  __builtin_amdgcn_global_load_lds(
      (const __attribute__((address_space(1))) unsigned int*)g,
      (__attribute__((address_space(3))) unsigned int*)l, 16, 0, 0);
}

// ---------------- weights f32 -> bf16 ----------------
__global__ void k_convert_w(const float* __restrict__ qkv_w,
                            const float* __restrict__ proj_w,
                            u16* __restrict__ wout) {
  int i = blockIdx.x * 256 + threadIdx.x;   // grid 1024 -> 262144 exactly
  if (i < 196608) wout[i] = f2bf(qkv_w[i]);
  else            wout[i] = f2bf(proj_w[i - 196608]);
}

// ---------------- GroupNorm stats: one block per (b,g) ----------------
__global__ __launch_bounds__(1024) void k_gn_stats(const float* __restrict__ x,
                                                   float* __restrict__ stats) {
  int grp = blockIdx.x;  // b*32+g ; 8 channels * 18432 contiguous f32
  const float4* p = (const float4*)(x + (size_t)grp * 147456);
  float s1 = 0.f, s2 = 0.f;
  for (int i = threadIdx.x; i < 36864; i += 1024) {
    float4 v = p[i];
    s1 += v.x + v.y + v.z + v.w;
    s2 += v.x*v.x + v.y*v.y + v.z*v.z + v.w*v.w;
  }
  for (int off = 1; off < 64; off <<= 1) {
    s1 += __shfl_xor(s1, off, 64);
    s2 += __shfl_xor(s2, off, 64);
  }
  __shared__ float ls1[16], ls2[16];
  int wid = threadIdx.x >> 6;
  if ((threadIdx.x & 63) == 0) { ls1[wid] = s1; ls2[wid] = s2; }
  __syncthreads();
  if (threadIdx.x == 0) {
    float a = 0.f, b = 0.f;
    for (int i = 0; i < 16; i++) { a += ls1[i]; b += ls2[i]; }
    float mu  = a / 147456.0f;
    float var = b / 147456.0f - mu * mu;
    stats[grp * 2]     = mu;
    stats[grp * 2 + 1] = rsqrtf(var + EPS_);
  }
}

// ---------------- normalize + transpose: x[b][c][n] f32 -> h_t[b][n][c] bf16 ----------------
__global__ __launch_bounds__(256) void k_tnorm(const float* __restrict__ x,
                                               const float* __restrict__ stats,
                                               const float* __restrict__ nw,
                                               const float* __restrict__ nb,
                                               u16* __restrict__ h_t) {
  __shared__ u16 tl[64 * 66];
  int wg = blockIdx.x;          // 2304 = b(2) * ct(4) * nt(288)
  int nt = wg % 288; int ct = (wg / 288) & 3; int b = wg / 1152;
  int c0 = ct * 64, n0 = nt * 64;
  int tid = threadIdx.x;
#pragma unroll
  for (int p = 0; p < 4; p++) {
    int c_l = p * 16 + (tid >> 4);
    int n4  = (tid & 15) * 4;
    int cg  = c0 + c_l;
    float4 v = *(const float4*)(x + ((size_t)(b * C_ + cg)) * ND_ + n0 + n4);
    float mu = stats[(b * G_ + (cg >> 3)) * 2];
    float rs = stats[(b * G_ + (cg >> 3)) * 2 + 1];
    float w = nw[cg], bia = nb[cg];
    tl[(n4 + 0) * 66 + c_l] = f2bf((v.x - mu) * rs * w + bia);
    tl[(n4 + 1) * 66 + c_l] = f2bf((v.y - mu) * rs * w + bia);
    tl[(n4 + 2) * 66 + c_l] = f2bf((v.z - mu) * rs * w + bia);
    tl[(n4 + 3) * 66 + c_l] = f2bf((v.w - mu) * rs * w + bia);
  }
  __syncthreads();
#pragma unroll
  for (int p = 0; p < 2; p++) {
    int idx = p * 256 + tid;
    int n_l = idx >> 3, c8 = idx & 7;
    const u32* s = (const u32*)((const char*)tl + n_l * 132 + c8 * 16);
    uint4 vv; vv.x = s[0]; vv.y = s[1]; vv.z = s[2]; vv.w = s[3];
    *(uint4*)(h_t + ((size_t)(b * ND_ + n0 + n_l)) * C_ + c0 + c8 * 8) = vv;
  }
}

// ---------------- QK GEMM (swapped: A=H [n x c], B=W^T [c x o]) ----------------
// Q -> q_ws [b][n][256] (prescaled); K -> k_ws fragment-linear:
// off_u16(slice, t, key, ch) = ((slice*48+t)*1536 + (ch>>3)*48 + key)*8 + (ch&7)
__global__ __launch_bounds__(256) void k_qk(const u16* __restrict__ h_t,
                                            const u16* __restrict__ w_qkv,
                                            const float* __restrict__ qkv_b,
                                            u16* __restrict__ q_ws,
                                            u16* __restrict__ k_ws) {
  int wg = blockIdx.x;
  int nt = wg % 288; int ot = (wg / 288) & 3; int b = wg / 1152;
  int n0 = nt * 64, o0 = ot * 128;
  int lane = threadIdx.x & 63; int w = threadIdx.x >> 6;
  int g = lane >> 4, lid = lane & 15;
  int n_w = n0 + w * 16;
  f32x4 acc[8];
#pragma unroll
  for (int t = 0; t < 8; t++) acc[t] = (f32x4){0.f, 0.f, 0.f, 0.f};
  const short8* Ab = (const short8*)(h_t + ((size_t)(b * ND_ + n_w + lid)) * C_ + g * 8);
#pragma unroll
  for (int ks = 0; ks < 8; ks++) {
    short8 a = Ab[ks * 4];
#pragma unroll
    for (int t = 0; t < 8; t++) {
      short8 bf = *(const short8*)(w_qkv + ((size_t)(o0 + t * 16 + lid)) * C_ + ks * 32 + g * 8);
      acc[t] = __builtin_amdgcn_mfma_f32_16x16x32_bf16(a, bf, acc[t], 0, 0, 0);
    }
  }
  if (o0 < 256) {   // Q path (uniform per block)
#pragma unroll
    for (int t = 0; t < 8; t++) {
      int o_t = o0 + t * 16;
      float bias = qkv_b[o_t + lid];
#pragma unroll
      for (int r = 0; r < 4; r++) {
        int n_idx = n_w + g * 4 + r;
        q_ws[((size_t)(b * ND_ + n_idx)) * C_ + o_t + lid] = f2bf((acc[t][r] + bias) * QS2_);
      }
    }
  } else {          // K path -> fragment-linear layout
#pragma unroll
    for (int t = 0; t < 8; t++) {
      int o_t = o0 + t * 16;
      float bias = qkv_b[o_t + lid];
      int oc = o_t - 256 + lid;
#pragma unroll
      for (int r = 0; r < 4; r++) {
        int n_idx = n_w + g * 4 + r;
        int dd = n_idx / 2304, hw = n_idx % 2304;
        int tt = hw / 48, kk = hw % 48;
        size_t off = ((size_t)((b * 8 + dd) * 48 + tt) * 1536 + (oc >> 3) * 48 + kk) * 8 + (oc & 7);
        k_ws[off] = f2bf(acc[t][r] + bias);
      }
    }
  }
}

// ---------------- V GEMM -> v_ws group-major [slice][grp48][slot6][c256][8] ----------------
__global__ __launch_bounds__(256) void k_v(const u16* __restrict__ h_t,
                                           const u16* __restrict__ w_qkv,
                                           const float* __restrict__ qkv_b,
                                           u16* __restrict__ v_ws) {
  int wg = blockIdx.x;
  int nt = wg % 144; int ot = (wg / 144) & 3; int b = wg / 576;
  int n0 = nt * 128, o0 = ot * 64;
  int lane = threadIdx.x & 63; int w = threadIdx.x >> 6;
  int g = lane >> 4, lid = lane & 15;
  int o_w = o0 + w * 16;
  f32x4 acc[8];
#pragma unroll
  for (int t = 0; t < 8; t++) acc[t] = (f32x4){0.f, 0.f, 0.f, 0.f};
  const short8* Ab = (const short8*)(w_qkv + ((size_t)(512 + o_w + lid)) * C_ + g * 8);
#pragma unroll
  for (int ks = 0; ks < 8; ks++) {
    short8 a = Ab[ks * 4];
#pragma unroll
    for (int t = 0; t < 8; t++) {
      short8 bf = *(const short8*)(h_t + ((size_t)(b * ND_ + n0 + t * 16 + lid)) * C_ + ks * 32 + g * 8);
      acc[t] = __builtin_amdgcn_mfma_f32_16x16x32_bf16(a, bf, acc[t], 0, 0, 0);
    }
  }
#pragma unroll
  for (int t = 0; t < 8; t++) {
#pragma unroll
    for (int r = 0; r < 4; r++) {
      int o = o_w + g * 4 + r;
      int n = n0 + t * 16 + lid;
      int d = n / 2304; int hw = n % 2304;
      int grp = hw / 48; int j = hw % 48;
      size_t idx = ((size_t)(((b * 8 + d) * 48 + grp) * 6 + (j >> 3))) * 2048 + o * 8 + (j & 7);
      v_ws[idx] = f2bf(acc[t][r] + qkv_b[512 + o]);
    }
  }
}

// ---------------- fused attention: 576 blocks x 2 waves x 32q, KVBLK=48 ----------------
__global__ __launch_bounds__(128, 2) void k_attn(const u16* __restrict__ q_ws,
                                                 const u16* __restrict__ k_ws,
                                                 const u16* __restrict__ v_ws,
                                                 u16* __restrict__ ao) {
  // K double buffer: 2 x 24KB fragment-linear tiles + 1KB guard for pad-row reads
  __shared__ __align__(16) unsigned char lds[50176];
  int wg = blockIdx.x;
  int virt = (wg & 7) * 72 + (wg >> 3);   // XCD-affine: XCD x -> slices 2x..2x+1
  int slice = virt / 36;                  // 0..15
  int qt = virt % 36;                     // 0..35 (64 q each)
  int b = slice >> 3, d = slice & 7;
  int tid = threadIdx.x;
  int lane = tid & 63, w = tid >> 6;
  int l31 = lane & 31, hi = lane >> 5;

  const char* kgb = (const char*)k_ws + (size_t)slice * 1179648;
  const char* vgb = (const char*)v_ws + (size_t)slice * 1179648;

  // hoist Q fragments (32 q per wave; prescaled by softmax-scale*log2e)
  size_t nbase = (size_t)b * ND_ + d * HW_ + qt * 64 + w * 32;
  const char* qp = (const char*)q_ws + (nbase + l31) * 512 + hi * 16;
  short8 qf[16];
#pragma unroll
  for (int ks = 0; ks < 16; ks++) qf[ks] = *(const short8*)(qp + ks * 32);

  f32x16 acc[8];
#pragma unroll
  for (int i = 0; i < 8; i++) acc[i] = (f32x16)0.0f;

  // stage tile t into buffer bb (linear both sides; 12 x 16B per thread)
#define STAGE_K(t_, bb_) {                                            \
    const char* src_ = kgb + (size_t)(t_) * 24576 + tid * 16;         \
    char* dst_ = (char*)lds + (bb_) * 24576 + w * 1024;               \
    _Pragma("unroll")                                                 \
    for (int i_ = 0; i_ < 12; i_++)                                   \
      gll16(src_ + i_ * 2048, dst_ + i_ * 2048);                      \
  }

  STAGE_K(0, 0);
  __syncthreads();

  for (int t = 0; t < 48; t++) {
    int ba = t & 1;
    if (t < 47) STAGE_K(t + 1, ba ^ 1);

    // QK^T swapped: S[key][q] ; K tile fragment-linear: slot*768 + key*16
    const char* kb = (const char*)lds + ba * 24576;
    f32x16 S0 = (f32x16)0.0f, S1 = (f32x16)0.0f;
#pragma unroll
    for (int ks = 0; ks < 16; ks++) {
      const char* p = kb + (ks * 2 + hi) * 768 + l31 * 16;
      short8 k0 = *(const short8*)(p);
      short8 k1 = *(const short8*)(p + 512);   // keys 32..47 (+16 pad rows, dead)
      S0 = __builtin_amdgcn_mfma_f32_32x32x16_bf16(k0, qf[ks], S0, 0, 0, 0);
      S1 = __builtin_amdgcn_mfma_f32_32x32x16_bf16(k1, qf[ks], S1, 0, 0, 0);
    }

    // exact softmax over the 48 keys (one group), lane-local + one half-swap
#pragma unroll
    for (int r = 0; r < 16; r++) S0[r] = __builtin_amdgcn_exp2f(S0[r]);
#pragma unroll
    for (int r = 0; r < 8; r++)  S1[r] = __builtin_amdgcn_exp2f(S1[r]);
    float z = 0.f;
#pragma unroll
    for (int r = 0; r < 16; r++) z += S0[r];
#pragma unroll
    for (int r = 0; r < 8; r++)  z += S1[r];
    z += __shfl_xor(z, 32, 64);
    float inv = __builtin_amdgcn_rcpf(z);
#pragma unroll
    for (int r = 0; r < 16; r++) S0[r] *= inv;
#pragma unroll
    for (int r = 0; r < 8; r++)  S1[r] *= inv;

    // pack P -> PV A-fragments (cvt_pk + permlane32_swap)
    short8 pa[3];
#pragma unroll
    for (int s = 0; s < 3; s++) {
      const f32x16& P = (s < 2) ? S0 : S1;
      const int a = (s == 1) ? 8 : 0;
      u32 u0, u1, v0, v1;
      asm("v_cvt_pk_bf16_f32 %0, %1, %2" : "=v"(u0) : "v"(P[a + 0]), "v"(P[a + 1]));
      asm("v_cvt_pk_bf16_f32 %0, %1, %2" : "=v"(u1) : "v"(P[a + 2]), "v"(P[a + 3]));
      asm("v_cvt_pk_bf16_f32 %0, %1, %2" : "=v"(v0) : "v"(P[a + 4]), "v"(P[a + 5]));
      asm("v_cvt_pk_bf16_f32 %0, %1, %2" : "=v"(v1) : "v"(P[a + 6]), "v"(P[a + 7]));
      asm("v_permlane32_swap_b32 %0, %1" : "+v"(u0), "+v"(v0));
      asm("v_permlane32_swap_b32 %0, %1" : "+v"(u1), "+v"(v1));
      u32x4 wv; wv[0] = u0; wv[1] = u1; wv[2] = v0; wv[3] = v1;
      pa[s] = __builtin_bit_cast(short8, wv);
    }

    // PV: V fragments straight from L2 (group-major layout, contiguous 512B/half-wave)
    const char* vt = vgb + (size_t)t * 24576;
#pragma unroll
    for (int s = 0; s < 3; s++) {
      const char* vs = vt + (s * 2 + hi) * 4096 + l31 * 16;
#pragma unroll
      for (int ct = 0; ct < 8; ct++) {
        short8 vf = *(const short8*)(vs + ct * 512);
        acc[ct] = __builtin_amdgcn_mfma_f32_32x32x16_bf16(pa[s], vf, acc[ct], 0, 0, 0);
      }
    }
    __syncthreads();
  }

  // epilogue: D layout col=lane&31 (=q? no: col = B-cols = q), row=key... here:
  // out tile O[q32][c256]: col=l31 is c? A=pa(q rows), B=V(c cols) -> col=c, row=q.
#pragma unroll
  for (int ct = 0; ct < 8; ct++) {
#pragma unroll
    for (int r = 0; r < 16; r++) {
      int ql = (r & 3) + 8 * (r >> 2) + 4 * hi;
      ao[(nbase + ql) * 256 + ct * 32 + l31] = f2bf(acc[ct][r]);
    }
  }
}

// ---------------- proj + bias + residual -> d_out f32 channel-major ----------------
__global__ __launch_bounds__(256) void k_proj(const u16* __restrict__ ao,
                                              const u16* __restrict__ w_p,
                                              const float* __restrict__ proj_b,
                                              const float* __restrict__ x,
                                              float* __restrict__ out) {
  int wg = blockIdx.x;
  int nt = wg % 144; int ot = (wg / 144) & 3; int b = wg / 576;
  int n0 = nt * 128, o0 = ot * 64;
  int lane = threadIdx.x & 63; int w = threadIdx.x >> 6;
  int g = lane >> 4, lid = lane & 15;
  int o_w = o0 + w * 16;
  f32x4 acc[8];
#pragma unroll
  for (int t = 0; t < 8; t++) acc[t] = (f32x4){0.f, 0.f, 0.f, 0.f};
  const short8* Ab = (const short8*)(w_p + ((size_t)(o_w + lid)) * C_ + g * 8);
#pragma unroll
  for (int ks = 0; ks < 8; ks++) {
    short8 a = Ab[ks * 4];
#pragma unroll
    for (int t = 0; t < 8; t++) {
      short8 bf = *(const short8*)(ao + ((size_t)(b * ND_ + n0 + t * 16 + lid)) * C_ + ks * 32 + g * 8);
      acc[t] = __builtin_amdgcn_mfma_f32_16x16x32_bf16(a, bf, acc[t], 0, 0, 0);
    }
  }
#pragma unroll
  for (int t = 0; t < 8; t++) {
#pragma unroll
    for (int r = 0; r < 4; r++) {
      int o = o_w + g * 4 + r;
      size_t off = ((size_t)(b * C_ + o)) * ND_ + n0 + t * 16 + lid;
      out[off] = acc[t][r] + proj_b[o] + x[off];
    }
  }
}

extern "C" void kernel_launch(void* const* d_in, const int* in_sizes, int n_in,
                              void* d_out, int out_size, void* d_ws, size_t ws_size,
                              hipStream_t stream) {
  const float* x      = (const float*)d_in[0];
  const float* norm_w = (const float*)d_in[1];
  const float* norm_b = (const float*)d_in[2];
  const float* qkv_w  = (const float*)d_in[3];
  const float* qkv_b  = (const float*)d_in[4];
  const float* proj_w = (const float*)d_in[5];
  const float* proj_b = (const float*)d_in[6];

  char* ws = (char*)d_ws;
  float* stats = (float*)ws;
  u16* w_qkv = (u16*)(ws + 1024);
  u16* w_p   = (u16*)(ws + 1024 + 393216);
  u16* h_t   = (u16*)(ws + 525312);
  u16* q_ws  = h_t + 9437184;
  u16* k_ws  = q_ws + 9437184;
  u16* v_ws  = k_ws + 9437184;
  u16* ao    = h_t;  // alias: h_t dead after k_v
  float* out = (float*)d_out;

  if (ws_size < (size_t)525312 + 4ull * 9437184ull * 2ull) return;

  hipLaunchKernelGGL(k_convert_w, dim3(1024), dim3(256), 0, stream, qkv_w, proj_w, w_qkv);
  hipLaunchKernelGGL(k_gn_stats,  dim3(64),   dim3(1024), 0, stream, x, stats);
  hipLaunchKernelGGL(k_tnorm,     dim3(2304), dim3(256), 0, stream, x, stats, norm_w, norm_b, h_t);
  hipLaunchKernelGGL(k_qk,        dim3(2304), dim3(256), 0, stream, h_t, w_qkv, qkv_b, q_ws, k_ws);
  hipLaunchKernelGGL(k_v,         dim3(1152), dim3(256), 0, stream, h_t, w_qkv, qkv_b, v_ws);
  hipLaunchKernelGGL(k_attn,      dim3(576),  dim3(128), 0, stream, q_ws, k_ws, v_ws, ao);
  hipLaunchKernelGGL(k_proj,      dim3(1152), dim3(256), 0, stream, ao, w_p, proj_b, x, out);
}